// Round 5
// baseline (715.257 us; speedup 1.0000x reference)
//
#include <hip/hip_runtime.h>
#include <stdint.h>
#include <math.h>

// Problem constants (fixed by reference file)
#define NROWS 32768     // B*S = 8*4096
#define DIM   256
#define KCODES 8192
#define BETA  0.25f
#define CSPLIT 4        // code splits across gemm grid.y
#define NELEM 8388608   // NROWS*DIM

typedef float f32x4 __attribute__((ext_vector_type(4)));
typedef _Float16 v8h __attribute__((ext_vector_type(8)));
typedef unsigned short us4 __attribute__((ext_vector_type(4)));

// ---------- fp16 two-term split (Ootomo): x ~= hi + lo, err ~2.4e-7*|x| ----------
__device__ inline unsigned int split1(float x) {
    _Float16 hf = (_Float16)x;
    _Float16 lf = (_Float16)(x - (float)hf);
    unsigned int h = __builtin_bit_cast(unsigned short, hf);
    unsigned int l = __builtin_bit_cast(unsigned short, lf);
    return h | (l << 16);
}

__device__ inline void gload_lds16(const void* g, void* l) {
    // async global->LDS, 16B per lane; LDS dest = wave-uniform base + lane*16
    __builtin_amdgcn_global_load_lds(
        (const __attribute__((address_space(1))) void*)g,
        (__attribute__((address_space(3))) void*)l,
        16, 0, 0);
}

// ---------- prep: z -> (z_hi, z_lo) fp16 ----------
__global__ void prep_z(const float* __restrict__ z,
                       unsigned short* __restrict__ zhi,
                       unsigned short* __restrict__ zlo) {
    int t = blockIdx.x * blockDim.x + threadIdx.x;   // 0..NELEM/4-1
    float4 v = reinterpret_cast<const float4*>(z)[t];
    unsigned int p0 = split1(v.x);
    unsigned int p1 = split1(v.y);
    unsigned int p2 = split1(v.z);
    unsigned int p3 = split1(v.w);
    us4 h, l;
    h[0] = (unsigned short)p0; l[0] = (unsigned short)(p0 >> 16);
    h[1] = (unsigned short)p1; l[1] = (unsigned short)(p1 >> 16);
    h[2] = (unsigned short)p2; l[2] = (unsigned short)(p2 >> 16);
    h[3] = (unsigned short)p3; l[3] = (unsigned short)(p3 >> 16);
    reinterpret_cast<us4*>(zhi)[t] = h;
    reinterpret_cast<us4*>(zlo)[t] = l;
}

// ---------- prep: embed -> (e_hi, e_lo) fp16 + 0.5*||e||^2 fp32 ----------
__global__ void prep_e(const float* __restrict__ e,
                       unsigned short* __restrict__ ehi,
                       unsigned short* __restrict__ elo,
                       float* __restrict__ enrm) {
    int row = blockIdx.x;      // 0..KCODES-1
    int d = threadIdx.x;       // 0..255
    float x = e[(size_t)row * DIM + d];
    unsigned int p = split1(x);
    ehi[(size_t)row * DIM + d] = (unsigned short)p;
    elo[(size_t)row * DIM + d] = (unsigned short)(p >> 16);
    float sq = x * x;
    #pragma unroll
    for (int off = 32; off; off >>= 1) sq += __shfl_down(sq, off);
    __shared__ float ps[4];
    if ((threadIdx.x & 63) == 0) ps[threadIdx.x >> 6] = sq;
    __syncthreads();
    if (threadIdx.x == 0) enrm[row] = 0.5f * (ps[0] + ps[1] + ps[2] + ps[3]);
}

// ---------- fused split-GEMM (K=768) + per-row argmin over this block's codes ----------
// score(n,k) = 0.5||e_k||^2 - z_n . e_k   (|| z ||^2 dropped: row-constant)
// A' = [z_hi | z_hi | z_lo], B' = [e_hi | e_lo | e_hi]  -> 3-term product in one GEMM
// BK=128 halves, single-buffered 2-barrier K-loop (explicit dbuf regressed in R3;
// occupancy already 2 blocks/CU so 64KB LDS costs nothing -- m132's cliff N/A).
// LDS: 16 16B-groups/row, phys_group = g ^ (row&15); fragment reads spread 16 lanes
// over all 16 groups (2 lanes/bank-quad = free, m136). Reduction arrays alias As.
__launch_bounds__(256)
__global__ void gemm_argmin(const unsigned short* __restrict__ zhi,
                            const unsigned short* __restrict__ zlo,
                            const unsigned short* __restrict__ ehi,
                            const unsigned short* __restrict__ elo,
                            const float* __restrict__ enrm,
                            float* __restrict__ pval,
                            int* __restrict__ pcol) {
    __shared__ __align__(16) unsigned short As[128 * 128];   // 32 KB
    __shared__ __align__(16) unsigned short Bs[128 * 128];   // 32 KB  (total = 64 KB)

    const int tid = threadIdx.x;
    const int w = tid >> 6, l = tid & 63;
    const int lx = l & 15, quad = l >> 4;
    const int wm = w >> 1, wn = w & 1;
    const int rowblk = blockIdx.x;   // 0..255
    const int cs = blockIdx.y;       // 0..3

    const int arow_base = rowblk * 128;
    const int cbase_cs = cs * (KCODES / CSPLIT);

    float runv[16];
    int runc[16];
    #pragma unroll
    for (int s = 0; s < 16; ++s) { runv[s] = 3.0e38f; runc[s] = 0x7fffffff; }

    // staging: each wave-issue covers 4 rows x 16 groups (1 KB); 8 issues per matrix
    const int st_r4 = l >> 4;                                // row within 4-row chunk

    for (int nt = 0; nt < (KCODES / CSPLIT) / 128; ++nt) {   // 16 N-tiles
        const int colbase = cbase_cs + nt * 128;
        f32x4 acc[4][4];
        #pragma unroll
        for (int mi = 0; mi < 4; ++mi)
            #pragma unroll
            for (int ni = 0; ni < 4; ++ni) {
                f32x4 zz = {0.f, 0.f, 0.f, 0.f};
                acc[mi][ni] = zz;
            }

        #pragma unroll
        for (int seg = 0; seg < 3; ++seg) {   // [zhi*ehi | zhi*elo | zlo*ehi]
            const unsigned short* za = (seg == 2) ? zlo : zhi;
            const unsigned short* eb = (seg == 1) ? elo : ehi;

            #pragma unroll
            for (int bk = 0; bk < 2; ++bk) {   // 2 x BK=128 halves per seg
                const int ao = bk * 128;
                __syncthreads();   // prior reads done before overwrite
                #pragma unroll
                for (int i = 0; i < 8; ++i) {
                    const int r = w * 32 + i * 4 + st_r4;           // tile row
                    const int g = (l & 15) ^ (r & 15);              // logical group
                    const int goff = ao + g * 8;                    // halves
                    gload_lds16(za + (size_t)(arow_base + r) * DIM + goff,
                                &As[(w * 32 + i * 4) * 128]);
                    gload_lds16(eb + (size_t)(colbase + r) * DIM + goff,
                                &Bs[(w * 32 + i * 4) * 128]);
                }
                __syncthreads();   // staged data visible

                #pragma unroll
                for (int kc = 0; kc < 4; ++kc) {
                    const int gsw = ((kc * 4 + quad) ^ lx) * 8;
                    v8h af[4], bfr[4];
                    #pragma unroll
                    for (int mi = 0; mi < 4; ++mi)
                        af[mi] = *(const v8h*)&As[(wm * 64 + mi * 16 + lx) * 128 + gsw];
                    #pragma unroll
                    for (int ni = 0; ni < 4; ++ni)
                        bfr[ni] = *(const v8h*)&Bs[(wn * 64 + ni * 16 + lx) * 128 + gsw];
                    #pragma unroll
                    for (int mi = 0; mi < 4; ++mi)
                        #pragma unroll
                        for (int ni = 0; ni < 4; ++ni)
                            acc[mi][ni] = __builtin_amdgcn_mfma_f32_16x16x32_f16(
                                af[mi], bfr[ni], acc[mi][ni], 0, 0, 0);
                }
            }
        }

        // epilogue: score = enrm[col] - dot; update running per-lane argmin
        #pragma unroll
        for (int ni = 0; ni < 4; ++ni) {
            const int col = colbase + wn * 64 + ni * 16 + lx;
            const float es = enrm[col];
            #pragma unroll
            for (int mi = 0; mi < 4; ++mi)
                #pragma unroll
                for (int r = 0; r < 4; ++r) {
                    float sv = es - acc[mi][ni][r];
                    const int s = mi * 4 + r;
                    if (sv < runv[s]) { runv[s] = sv; runc[s] = col; }
                }
        }
    }

    // cross-lane reduce (16 lanes of a quad-group hold 16 col-positions of same row)
    // reduction arrays alias the (now-dead) As tile
    float (*rv)[128] = (float (*)[128])&As[0];        // 2*128 f32 = 1 KB
    int   (*rc)[128] = (int   (*)[128])&As[1024];     // 2*128 i32 = 1 KB
    __syncthreads();   // all LDS tile reads done before aliasing
    #pragma unroll
    for (int s = 0; s < 16; ++s) {
        float v = runv[s]; int c = runc[s];
        #pragma unroll
        for (int m = 1; m < 16; m <<= 1) {
            float ov = __shfl_xor(v, m);
            int oc = __shfl_xor(c, m);
            if (ov < v || (ov == v && oc < c)) { v = ov; c = oc; }
        }
        if (lx == 0) {
            const int mi = s >> 2, r = s & 3;
            const int rl = wm * 64 + mi * 16 + quad * 4 + r;
            rv[wn][rl] = v; rc[wn][rl] = c;
        }
    }
    __syncthreads();
    if (tid < 128) {
        float v0 = rv[0][tid]; int c0 = rc[0][tid];
        float v1 = rv[1][tid]; int c1 = rc[1][tid];
        if (v1 < v0 || (v1 == v0 && c1 < c0)) { v0 = v1; c0 = c1; }
        const size_t row = (size_t)arow_base + tid;
        pval[row * CSPLIT + cs] = v0;
        pcol[row * CSPLIT + cs] = c0;
    }
}

// ---------- fused: merge code-split partials + gather + loss + histogram ----------
__global__ void fused_out(const float* __restrict__ pval,
                          const int* __restrict__ pcol,
                          const float* __restrict__ z,
                          const float* __restrict__ embed,
                          float* __restrict__ out_zq,
                          float* __restrict__ out_idx,
                          float* __restrict__ counts,
                          float* __restrict__ lossAcc) {
    __shared__ int cidx[16];
    const int tid = threadIdx.x;
    if (tid < 16) {
        const int row = blockIdx.x * 16 + tid;
        float bv = pval[row * CSPLIT]; int bc = pcol[row * CSPLIT];
        #pragma unroll
        for (int cs = 1; cs < CSPLIT; ++cs) {
            float v = pval[row * CSPLIT + cs]; int c = pcol[row * CSPLIT + cs];
            if (v < bv || (v == bv && c < bc)) { bv = v; bc = c; }
        }
        cidx[tid] = bc;
        out_idx[row] = (float)bc;
        atomicAdd(&counts[bc], 1.0f);
    }
    __syncthreads();
    const int d = tid;
    float ls = 0.f;
    #pragma unroll 4
    for (int i = 0; i < 16; ++i) {
        const int row = blockIdx.x * 16 + i;
        const int c = cidx[i];
        const float zv = z[(size_t)row * DIM + d];
        const float ev = embed[(size_t)c * DIM + d];
        const float diff = ev - zv;
        out_zq[(size_t)row * DIM + d] = zv + diff;
        ls += diff * diff;
    }
    #pragma unroll
    for (int off = 32; off; off >>= 1) ls += __shfl_down(ls, off);
    __shared__ float ps[4];
    if ((tid & 63) == 0) ps[tid >> 6] = ls;
    __syncthreads();
    if (tid == 0) atomicAdd(lossAcc, ps[0] + ps[1] + ps[2] + ps[3]);
}

// ---------- loss scale + perplexity ----------
__global__ void finalize(const float* __restrict__ counts,
                         const float* __restrict__ lossAcc,
                         float* __restrict__ out_loss,
                         float* __restrict__ out_perp) {
    float h = 0.f;
    for (int k = threadIdx.x; k < KCODES; k += 256) {
        float p = counts[k] * (1.0f / (float)NROWS);
        h += p * logf(p + 1e-12f);
    }
    #pragma unroll
    for (int off = 32; off; off >>= 1) h += __shfl_down(h, off);
    __shared__ float ps[4];
    if ((threadIdx.x & 63) == 0) ps[threadIdx.x >> 6] = h;
    __syncthreads();
    if (threadIdx.x == 0) {
        *out_perp = expf(-(ps[0] + ps[1] + ps[2] + ps[3]));
        *out_loss = BETA * lossAcc[0] / (float)NELEM;
    }
}

extern "C" void kernel_launch(void* const* d_in, const int* in_sizes, int n_in,
                              void* d_out, int out_size, void* d_ws, size_t ws_size,
                              hipStream_t stream) {
    const float* z = (const float*)d_in[0];       // [32768, 256] f32
    const float* embed = (const float*)d_in[1];   // [8192, 256] f32
    char* ws = (char*)d_ws;

    // workspace layout (all offsets 16B-aligned), total ~43.2 MB
    unsigned short* zhi = (unsigned short*)(ws + 0);          // 16 MB
    unsigned short* zlo = (unsigned short*)(ws + 16777216);   // 16 MB
    unsigned short* ehi = (unsigned short*)(ws + 33554432);   // 4 MB
    unsigned short* elo = (unsigned short*)(ws + 37748736);   // 4 MB
    float* enrm   = (float*)(ws + 41943040);                  // 32 KB
    float* pval   = (float*)(ws + 41975808);                  // 512 KB
    int*   pcol   = (int*)  (ws + 42500096);                  // 512 KB
    float* counts = (float*)(ws + 43155456);                  // 32 KB
    float* lossAcc = (float*)(ws + 43188224);                 // 4 B

    float* out = (float*)d_out;
    float* out_zq   = out;                 // 8388608
    float* out_loss = out + 8388608;       // 1
    float* out_perp = out + 8388609;       // 1
    float* out_idx  = out + 8388610;       // 32768 (indices as f32)

    // zero histogram + loss accumulator (ws is poisoned 0xAA before each call)
    (void)hipMemsetAsync(counts, 0, KCODES * 4 + 4, stream);

    prep_z<<<NELEM / 4 / 256, 256, 0, stream>>>(z, zhi, zlo);
    prep_e<<<KCODES, 256, 0, stream>>>(embed, ehi, elo, enrm);
    gemm_argmin<<<dim3(NROWS / 128, CSPLIT), 256, 0, stream>>>(
        zhi, zlo, ehi, elo, enrm, pval, pcol);
    fused_out<<<NROWS / 16, 256, 0, stream>>>(pval, pcol, z, embed,
                                              out_zq, out_idx, counts, lossAcc);
    finalize<<<1, 256, 0, stream>>>(counts, lossAcc, out_loss, out_perp);
}

// Round 6
// 547.503 us; speedup vs baseline: 1.3064x; 1.3064x over previous
//
#include <hip/hip_runtime.h>
#include <stdint.h>
#include <math.h>

// Problem constants (fixed by reference file)
#define NROWS 32768     // B*S = 8*4096
#define DIM   256
#define KCODES 8192
#define BETA  0.25f
#define CSPLIT 4        // code splits across gemm grid.y
#define NELEM 8388608   // NROWS*DIM

typedef float f32x4 __attribute__((ext_vector_type(4)));
typedef _Float16 v8h __attribute__((ext_vector_type(8)));
typedef unsigned short us4 __attribute__((ext_vector_type(4)));

// ---------- fp16 two-term split (Ootomo): x ~= hi + lo, err ~2.4e-7*|x| ----------
__device__ inline unsigned int split1(float x) {
    _Float16 hf = (_Float16)x;
    _Float16 lf = (_Float16)(x - (float)hf);
    unsigned int h = __builtin_bit_cast(unsigned short, hf);
    unsigned int l = __builtin_bit_cast(unsigned short, lf);
    return h | (l << 16);
}

__device__ inline void gload_lds16(const void* g, void* l) {
    // async global->LDS, 16B per lane; LDS dest = wave-uniform base + lane*16
    __builtin_amdgcn_global_load_lds(
        (const __attribute__((address_space(1))) void*)g,
        (__attribute__((address_space(3))) void*)l,
        16, 0, 0);
}

// ---------- prep: z -> (z_hi, z_lo) fp16 ----------
__global__ void prep_z(const float* __restrict__ z,
                       unsigned short* __restrict__ zhi,
                       unsigned short* __restrict__ zlo) {
    int t = blockIdx.x * blockDim.x + threadIdx.x;   // 0..NELEM/4-1
    float4 v = reinterpret_cast<const float4*>(z)[t];
    unsigned int p0 = split1(v.x);
    unsigned int p1 = split1(v.y);
    unsigned int p2 = split1(v.z);
    unsigned int p3 = split1(v.w);
    us4 h, l;
    h[0] = (unsigned short)p0; l[0] = (unsigned short)(p0 >> 16);
    h[1] = (unsigned short)p1; l[1] = (unsigned short)(p1 >> 16);
    h[2] = (unsigned short)p2; l[2] = (unsigned short)(p2 >> 16);
    h[3] = (unsigned short)p3; l[3] = (unsigned short)(p3 >> 16);
    reinterpret_cast<us4*>(zhi)[t] = h;
    reinterpret_cast<us4*>(zlo)[t] = l;
}

// ---------- prep: embed -> (e_hi, e_lo) fp16 + 0.5*||e||^2 fp32 ----------
__global__ void prep_e(const float* __restrict__ e,
                       unsigned short* __restrict__ ehi,
                       unsigned short* __restrict__ elo,
                       float* __restrict__ enrm) {
    int row = blockIdx.x;      // 0..KCODES-1
    int d = threadIdx.x;       // 0..255
    float x = e[(size_t)row * DIM + d];
    unsigned int p = split1(x);
    ehi[(size_t)row * DIM + d] = (unsigned short)p;
    elo[(size_t)row * DIM + d] = (unsigned short)(p >> 16);
    float sq = x * x;
    #pragma unroll
    for (int off = 32; off; off >>= 1) sq += __shfl_down(sq, off);
    __shared__ float ps[4];
    if ((threadIdx.x & 63) == 0) ps[threadIdx.x >> 6] = sq;
    __syncthreads();
    if (threadIdx.x == 0) enrm[row] = 0.5f * (ps[0] + ps[1] + ps[2] + ps[3]);
}

// ---------- fused split-GEMM (K=768) + per-row argmin over this block's codes ----------
// score(n,k) = 0.5||e_k||^2 - z_n . e_k   (|| z ||^2 dropped: row-constant)
// A' = [z_hi | z_hi | z_lo], B' = [e_hi | e_lo | e_hi]  -> 3-term product in one GEMM
// BK=64, single-buffered 2-barrier K-loop, 34 KB LDS -> 2 blocks/CU.
// (R3: explicit dbuf regressed; R5: BK=128/64KB LDS dropped to 1 block/CU, -52%.
//  This exact configuration measured 440 us / MfmaUtil 43% / 0 conflicts in R4.)
// LDS: 8 16B-groups/row, phys_group = g ^ (row&7) -> fragment reads 2-way max (free).
__launch_bounds__(256)
__global__ void gemm_argmin(const unsigned short* __restrict__ zhi,
                            const unsigned short* __restrict__ zlo,
                            const unsigned short* __restrict__ ehi,
                            const unsigned short* __restrict__ elo,
                            const float* __restrict__ enrm,
                            float* __restrict__ pval,
                            int* __restrict__ pcol) {
    __shared__ __align__(16) unsigned short As[128 * 64];   // 16 KB
    __shared__ __align__(16) unsigned short Bs[128 * 64];   // 16 KB
    __shared__ float rv[2][128];
    __shared__ int   rc[2][128];

    const int tid = threadIdx.x;
    const int w = tid >> 6, l = tid & 63;
    const int lx = l & 15, quad = l >> 4;
    const int wm = w >> 1, wn = w & 1;
    const int rowblk = blockIdx.x;   // 0..255
    const int cs = blockIdx.y;       // 0..3

    const int arow_base = rowblk * 128;
    const int cbase_cs = cs * (KCODES / CSPLIT);

    float runv[16];
    int runc[16];
    #pragma unroll
    for (int s = 0; s < 16; ++s) { runv[s] = 3.0e38f; runc[s] = 0x7fffffff; }

    // staging: per wave-issue, 64 lanes cover 8 rows x 8 groups (1 KB)
    const int st_row8 = l >> 3;                              // 0..7 row within issue
    const int st_g = (((l & 7) ^ (l >> 3)) * 8);             // swizzled global col (halves)
    const int fr_lx7 = lx & 7;                               // row&7 for fragment swizzle

    for (int nt = 0; nt < (KCODES / CSPLIT) / 128; ++nt) {   // 16 N-tiles
        const int colbase = cbase_cs + nt * 128;
        f32x4 acc[4][4];
        #pragma unroll
        for (int mi = 0; mi < 4; ++mi)
            #pragma unroll
            for (int ni = 0; ni < 4; ++ni) {
                f32x4 zz = {0.f, 0.f, 0.f, 0.f};
                acc[mi][ni] = zz;
            }

        #pragma unroll
        for (int seg = 0; seg < 3; ++seg) {   // [zhi*ehi | zhi*elo | zlo*ehi]
            const unsigned short* za = (seg == 2) ? zlo : zhi;
            const unsigned short* eb = (seg == 1) ? elo : ehi;

            for (int bk = 0; bk < 4; ++bk) {   // 4 x BK=64 = 256 halves per seg
                const int ao = bk * 64;
                __syncthreads();   // prior reads done before overwrite
                #pragma unroll
                for (int j = 0; j < 4; ++j) {
                    const int r = w * 32 + j * 8 + st_row8;
                    gload_lds16(za + (size_t)(arow_base + r) * DIM + ao + st_g,
                                &As[(w * 32 + j * 8) * 64]);
                    gload_lds16(eb + (size_t)(colbase + r) * DIM + ao + st_g,
                                &Bs[(w * 32 + j * 8) * 64]);
                }
                __syncthreads();   // staged data visible

                #pragma unroll
                for (int kc = 0; kc < 2; ++kc) {
                    const int gsw = ((kc * 4 + quad) ^ fr_lx7) * 8;
                    v8h af[4], bfr[4];
                    #pragma unroll
                    for (int mi = 0; mi < 4; ++mi)
                        af[mi] = *(const v8h*)&As[(wm * 64 + mi * 16 + lx) * 64 + gsw];
                    #pragma unroll
                    for (int ni = 0; ni < 4; ++ni)
                        bfr[ni] = *(const v8h*)&Bs[(wn * 64 + ni * 16 + lx) * 64 + gsw];
                    #pragma unroll
                    for (int mi = 0; mi < 4; ++mi)
                        #pragma unroll
                        for (int ni = 0; ni < 4; ++ni)
                            acc[mi][ni] = __builtin_amdgcn_mfma_f32_16x16x32_f16(
                                af[mi], bfr[ni], acc[mi][ni], 0, 0, 0);
                }
            }
        }

        // epilogue: score = enrm[col] - dot; update running per-lane argmin
        #pragma unroll
        for (int ni = 0; ni < 4; ++ni) {
            const int col = colbase + wn * 64 + ni * 16 + lx;
            const float es = enrm[col];
            #pragma unroll
            for (int mi = 0; mi < 4; ++mi)
                #pragma unroll
                for (int r = 0; r < 4; ++r) {
                    float sv = es - acc[mi][ni][r];
                    const int s = mi * 4 + r;
                    if (sv < runv[s]) { runv[s] = sv; runc[s] = col; }
                }
        }
    }

    // cross-lane reduce (16 lanes of a quad-group hold 16 col-positions of same row)
    #pragma unroll
    for (int s = 0; s < 16; ++s) {
        float v = runv[s]; int c = runc[s];
        #pragma unroll
        for (int m = 1; m < 16; m <<= 1) {
            float ov = __shfl_xor(v, m);
            int oc = __shfl_xor(c, m);
            if (ov < v || (ov == v && oc < c)) { v = ov; c = oc; }
        }
        if (lx == 0) {
            const int mi = s >> 2, r = s & 3;
            const int rl = wm * 64 + mi * 16 + quad * 4 + r;
            rv[wn][rl] = v; rc[wn][rl] = c;
        }
    }
    __syncthreads();
    if (tid < 128) {
        float v0 = rv[0][tid]; int c0 = rc[0][tid];
        float v1 = rv[1][tid]; int c1 = rc[1][tid];
        if (v1 < v0 || (v1 == v0 && c1 < c0)) { v0 = v1; c0 = c1; }
        const size_t row = (size_t)arow_base + tid;
        pval[row * CSPLIT + cs] = v0;
        pcol[row * CSPLIT + cs] = c0;
    }
}

// ---------- fused: merge code-split partials + gather + loss + histogram ----------
__global__ void fused_out(const float* __restrict__ pval,
                          const int* __restrict__ pcol,
                          const float* __restrict__ z,
                          const float* __restrict__ embed,
                          float* __restrict__ out_zq,
                          float* __restrict__ out_idx,
                          float* __restrict__ counts,
                          float* __restrict__ lossAcc) {
    __shared__ int cidx[16];
    const int tid = threadIdx.x;
    if (tid < 16) {
        const int row = blockIdx.x * 16 + tid;
        float bv = pval[row * CSPLIT]; int bc = pcol[row * CSPLIT];
        #pragma unroll
        for (int cs = 1; cs < CSPLIT; ++cs) {
            float v = pval[row * CSPLIT + cs]; int c = pcol[row * CSPLIT + cs];
            if (v < bv || (v == bv && c < bc)) { bv = v; bc = c; }
        }
        cidx[tid] = bc;
        out_idx[row] = (float)bc;
        atomicAdd(&counts[bc], 1.0f);
    }
    __syncthreads();
    const int d = tid;
    float ls = 0.f;
    #pragma unroll 4
    for (int i = 0; i < 16; ++i) {
        const int row = blockIdx.x * 16 + i;
        const int c = cidx[i];
        const float zv = z[(size_t)row * DIM + d];
        const float ev = embed[(size_t)c * DIM + d];
        const float diff = ev - zv;
        out_zq[(size_t)row * DIM + d] = zv + diff;
        ls += diff * diff;
    }
    #pragma unroll
    for (int off = 32; off; off >>= 1) ls += __shfl_down(ls, off);
    __shared__ float ps[4];
    if ((tid & 63) == 0) ps[tid >> 6] = ls;
    __syncthreads();
    if (tid == 0) atomicAdd(lossAcc, ps[0] + ps[1] + ps[2] + ps[3]);
}

// ---------- loss scale + perplexity ----------
__global__ void finalize(const float* __restrict__ counts,
                         const float* __restrict__ lossAcc,
                         float* __restrict__ out_loss,
                         float* __restrict__ out_perp) {
    float h = 0.f;
    for (int k = threadIdx.x; k < KCODES; k += 256) {
        float p = counts[k] * (1.0f / (float)NROWS);
        h += p * logf(p + 1e-12f);
    }
    #pragma unroll
    for (int off = 32; off; off >>= 1) h += __shfl_down(h, off);
    __shared__ float ps[4];
    if ((threadIdx.x & 63) == 0) ps[threadIdx.x >> 6] = h;
    __syncthreads();
    if (threadIdx.x == 0) {
        *out_perp = expf(-(ps[0] + ps[1] + ps[2] + ps[3]));
        *out_loss = BETA * lossAcc[0] / (float)NELEM;
    }
}

extern "C" void kernel_launch(void* const* d_in, const int* in_sizes, int n_in,
                              void* d_out, int out_size, void* d_ws, size_t ws_size,
                              hipStream_t stream) {
    const float* z = (const float*)d_in[0];       // [32768, 256] f32
    const float* embed = (const float*)d_in[1];   // [8192, 256] f32
    char* ws = (char*)d_ws;

    // workspace layout (all offsets 16B-aligned), total ~43.2 MB
    unsigned short* zhi = (unsigned short*)(ws + 0);          // 16 MB
    unsigned short* zlo = (unsigned short*)(ws + 16777216);   // 16 MB
    unsigned short* ehi = (unsigned short*)(ws + 33554432);   // 4 MB
    unsigned short* elo = (unsigned short*)(ws + 37748736);   // 4 MB
    float* enrm   = (float*)(ws + 41943040);                  // 32 KB
    float* pval   = (float*)(ws + 41975808);                  // 512 KB
    int*   pcol   = (int*)  (ws + 42500096);                  // 512 KB
    float* counts = (float*)(ws + 43155456);                  // 32 KB
    float* lossAcc = (float*)(ws + 43188224);                 // 4 B

    float* out = (float*)d_out;
    float* out_zq   = out;                 // 8388608
    float* out_loss = out + 8388608;       // 1
    float* out_perp = out + 8388609;       // 1
    float* out_idx  = out + 8388610;       // 32768 (indices as f32)

    // zero histogram + loss accumulator (ws is poisoned 0xAA before each call)
    (void)hipMemsetAsync(counts, 0, KCODES * 4 + 4, stream);

    prep_z<<<NELEM / 4 / 256, 256, 0, stream>>>(z, zhi, zlo);
    prep_e<<<KCODES, 256, 0, stream>>>(embed, ehi, elo, enrm);
    gemm_argmin<<<dim3(NROWS / 128, CSPLIT), 256, 0, stream>>>(
        zhi, zlo, ehi, elo, enrm, pval, pcol);
    fused_out<<<NROWS / 16, 256, 0, stream>>>(pval, pcol, z, embed,
                                              out_zq, out_idx, counts, lossAcc);
    finalize<<<1, 256, 0, stream>>>(counts, lossAcc, out_loss, out_perp);
}